// Round 9
// baseline (317.304 us; speedup 1.0000x reference)
//
#include <hip/hip_runtime.h>
#include <hip/hip_bf16.h>

#define N_NODES 50000
#define N_EDGES 1600000
#define NGRAPH  16
#define HID     128

#define RPB   128                           // rows per bucket
#define NB    ((N_NODES + RPB - 1) / RPB)   // 391 buckets
#define NBLK  256                           // partition blocks
#define EPB   ((N_EDGES + NBLK - 1) / NBLK) // 6250 edges per partition block
#define PLANESZ ((size_t)N_NODES * 64)      // fp8 plane: [N][64] bytes
#define GBLK  ((N_NODES * 64) / 256)        // gather blocks per plane = 12500

typedef unsigned int uint32;
typedef unsigned short ushort;
typedef unsigned char uchar;
typedef __attribute__((ext_vector_type(8))) short bf16x8;
typedef __attribute__((ext_vector_type(4))) float f32x4;
typedef __attribute__((ext_vector_type(2))) float f32x2;

// bf16 round-to-nearest-even helpers
__device__ __forceinline__ uint32 bf16r(float f) {
    uint32 b = __float_as_uint(f);
    return (b + 0x7fffu + ((b >> 16) & 1u)) >> 16;
}
__device__ __forceinline__ uint32 pack_bf16(float lo, float hi) {
    return bf16r(lo) | (bf16r(hi) << 16);
}
__device__ __forceinline__ float bf_lo(uint32 u) { return __uint_as_float(u << 16); }
__device__ __forceinline__ float bf_hi(uint32 u) { return __uint_as_float(u & 0xffff0000u); }

// ------- init (fused): zero accumulators+counters, graph bounds, weight pack, v3 -------
__global__ __launch_bounds__(256) void k_init(float* __restrict__ zp, int zn,
                                              const int* __restrict__ batch,
                                              int* __restrict__ gstart,
                                              const float* __restrict__ W2,
                                              const float* __restrict__ W7,
                                              const float* __restrict__ W3,
                                              const float* __restrict__ W4,
                                              ushort* __restrict__ wpack,
                                              float* __restrict__ v3) {
    int idx = blockIdx.x * 256 + threadIdx.x;
    if (idx < zn) zp[idx] = 0.f;
    if (idx <= NGRAPH) {
        int lo = 0, hi = N_NODES;
        while (lo < hi) {
            int mid = (lo + hi) >> 1;
            if (batch[mid] < idx) lo = mid + 1; else hi = mid;
        }
        gstart[idx] = lo;
    }
    if (idx < 4 * 16384) {
        int m = idx >> 14, f = idx & 16383;
        int j = f & 7, lane = (f >> 3) & 63, kk = (f >> 9) & 3, t = (f >> 11) & 7;
        int hp = t * 16 + (lane & 15);
        int k  = kk * 32 + ((lane >> 4) & 3) * 8 + j;
        const float* src = (m < 3) ? (W2 + m * HID * HID) : W7;
        wpack[idx] = (ushort)bf16r(src[hp * HID + k]);
    }
    if (idx < 3 * HID) {
        int l = idx / HID, hp = idx % HID;
        float acc = 0.f;
        for (int h = 0; h < HID; h++)
            acc += W3[l * HID * HID + hp * HID + h] * fmaxf(W4[l * HID + h], 0.f);
        v3[idx] = acc;
    }
}

// ---------------- P1: per-(bucket,block) histogram ----------------
__global__ __launch_bounds__(1024) void k_p1_hist(const int* __restrict__ row,
                                                  int* __restrict__ blkhist) {
    __shared__ int hist[NB];
    int tid = threadIdx.x, blk = blockIdx.x;
    for (int i = tid; i < NB; i += 1024) hist[i] = 0;
    __syncthreads();
    int s = blk * EPB, e = s + EPB; if (e > N_EDGES) e = N_EDGES;
    for (int i = s + tid; i < e; i += 1024)
        atomicAdd(&hist[row[i] >> 7], 1);
    __syncthreads();
    for (int i = tid; i < NB; i += 1024)
        blkhist[i * NBLK + blk] = hist[i];
}

// ------- P2 (fused): per-bucket scan over NBLK counts; last block scans bucket totals -------
__global__ __launch_bounds__(NBLK) void k_p2(int* __restrict__ blkhist,
                                             int* __restrict__ btot,
                                             int* __restrict__ bbase,
                                             int* __restrict__ done) {
    __shared__ int sums[NBLK];
    __shared__ int lastflag;
    int t = threadIdx.x, b = blockIdx.x;
    int v = blkhist[b * NBLK + t];
    sums[t] = v;
    __syncthreads();
    for (int d = 1; d < NBLK; d <<= 1) {
        int u = (t >= d) ? sums[t - d] : 0;
        __syncthreads();
        sums[t] += u;
        __syncthreads();
    }
    blkhist[b * NBLK + t] = sums[t] - v;     // local exclusive
    if (t == NBLK - 1) btot[b] = sums[t];    // bucket total
    if (t == 0) {
        __threadfence();
        int old = atomicAdd(done, 1);
        lastflag = (old == NB - 1);
    }
    __syncthreads();
    if (lastflag) {
        // final 391-wide scan, 2 entries/thread; coherent reads via atomic RMW
        int i0 = 2 * t, i1 = 2 * t + 1;
        int v0 = (i0 < NB) ? atomicAdd(&btot[i0], 0) : 0;
        int v1 = (i1 < NB) ? atomicAdd(&btot[i1], 0) : 0;
        int sum = v0 + v1;
        sums[t] = sum;
        __syncthreads();
        for (int d = 1; d < NBLK; d <<= 1) {
            int u = (t >= d) ? sums[t - d] : 0;
            __syncthreads();
            sums[t] += u;
            __syncthreads();
        }
        int excl = sums[t] - sum;
        if (i0 < NB) bbase[i0] = excl;
        if (i1 < NB) bbase[i1] = excl + v0;
        if (t == NBLK - 1) bbase[NB] = sums[t]; // == E
    }
}

// ------- P3: scatter int2{rowlocal:8|col:16, ea} into bucket runs (LDS cursors) -------
__global__ __launch_bounds__(1024) void k_p3_part(const int* __restrict__ row,
                                                  const int* __restrict__ col,
                                                  const float* __restrict__ ea,
                                                  const int* __restrict__ blkhist,
                                                  const int* __restrict__ bbase,
                                                  int2* __restrict__ pea) {
    __shared__ int cur[NB];
    int tid = threadIdx.x, blk = blockIdx.x;
    for (int i = tid; i < NB; i += 1024)
        cur[i] = bbase[i] + blkhist[i * NBLK + blk];
    __syncthreads();
    int s = blk * EPB, e = s + EPB; if (e > N_EDGES) e = N_EDGES;
    for (int i = s + tid; i < e; i += 1024) {
        int r = row[i], c = col[i];
        float a = ea[i];
        int slot = atomicAdd(&cur[r >> 7], 1);
        pea[slot] = make_int2(((r & (RPB - 1)) << 16) | c, __float_as_int(a));
    }
}

// ------- P4a: per-bucket counts + ea_sum + local scan -> offs, pxe -------
__global__ __launch_bounds__(512) void k_p4a(const int2* __restrict__ pea,
                                             const int* __restrict__ bbase,
                                             const float* __restrict__ x,
                                             int* __restrict__ offs,
                                             float* __restrict__ ea_sum,
                                             float2* __restrict__ pxe) {
    __shared__ int   cnt[RPB];
    __shared__ float eas[RPB];
    __shared__ int   scan_s[RPB];
    int tid = threadIdx.x, b = blockIdx.x;
    if (tid < RPB) { cnt[tid] = 0; eas[tid] = 0.f; }
    __syncthreads();
    int s = bbase[b], e = bbase[b + 1];
    for (int i = s + tid; i < e; i += 512) {
        int2 p = pea[i];
        int lr = ((uint32)p.x) >> 16;
        atomicAdd(&cnt[lr], 1);
        atomicAdd(&eas[lr], __int_as_float(p.y));
    }
    __syncthreads();
    if (tid < RPB) scan_s[tid] = cnt[tid];
    __syncthreads();
    for (int d = 1; d < RPB; d <<= 1) {
        int v = 0;
        if (tid < RPB && tid >= d) v = scan_s[tid - d];
        __syncthreads();
        if (tid < RPB) scan_s[tid] += v;
        __syncthreads();
    }
    int nbase = b * RPB;
    if (tid < RPB) {
        int excl = scan_s[tid] - cnt[tid];
        int n = nbase + tid;
        if (n < N_NODES) {
            offs[n] = s + excl;
            ea_sum[n] = eas[tid];
            pxe[n] = make_float2(x[n], eas[tid]);
        }
    }
    if (b == NB - 1 && tid == 0) offs[N_NODES] = e;
}

// ------- P4b: scatter csr + CSR-ordered payload pxec[slot] = pxe[col] -------
__global__ __launch_bounds__(512) void k_p4b(const int2* __restrict__ pea,
                                             const int* __restrict__ bbase,
                                             const int* __restrict__ offs,
                                             const float2* __restrict__ pxe,
                                             int* __restrict__ csr,
                                             float2* __restrict__ pxec) {
    __shared__ int cur[RPB];
    int tid = threadIdx.x, b = blockIdx.x;
    int nbase = b * RPB;
    if (tid < RPB) cur[tid] = (nbase + tid < N_NODES) ? offs[nbase + tid] : 0;
    __syncthreads();
    int s = bbase[b], e = bbase[b + 1];
    for (int i = s + tid; i < e; i += 512) {
        int2 p = pea[i];
        int c = p.x & 0xFFFF;
        int slot = atomicAdd(&cur[((uint32)p.x) >> 16], 1);
        csr[slot] = c;
        pxec[slot] = pxe[c];   // 400 KB table, L2-resident
    }
}

// ------- hop-1 gather by recompute, streaming CSR-ordered payload (no indirection) -------
__global__ __launch_bounds__(256) void k_gather1(const float2* __restrict__ pxec,
                                                 const int* __restrict__ offs,
                                                 const float* __restrict__ w1,
                                                 const float* __restrict__ v3,
                                                 uint32* __restrict__ agg) {
    int node = (blockIdx.x * 256 + threadIdx.x) >> 6;
    int lane = threadIdx.x & 63;
    if (node >= N_NODES) return;
    f32x2 w1v = {w1[2 * lane], w1[2 * lane + 1]};
    f32x2 v3v = {v3[2 * lane], v3[2 * lane + 1]};
    const f32x2 zero = {0.f, 0.f};
    int s = offs[node], e = offs[node + 1];
    f32x2 acc[4] = {zero, zero, zero, zero};
    int j = s;
    for (; j + 8 <= e; j += 8) {
        float2 p[8];
#pragma unroll
        for (int u = 0; u < 8; u++) p[u] = pxec[j + u];   // broadcast, contiguous
#pragma unroll
        for (int u = 0; u < 8; u++) {
            f32x2 px = {p[u].x, p[u].x};
            f32x2 pe = {p[u].y, p[u].y};
            f32x2 r = __builtin_elementwise_fma(px, w1v, pe * v3v);
            acc[u & 3] += __builtin_elementwise_max(r, zero);
        }
    }
    for (; j < e; j++) {
        float2 p = pxec[j];
        f32x2 px = {p.x, p.x};
        f32x2 pe = {p.y, p.y};
        f32x2 r = __builtin_elementwise_fma(px, w1v, pe * v3v);
        acc[0] += __builtin_elementwise_max(r, zero);
    }
    f32x2 rs = (acc[0] + acc[1]) + (acc[2] + acc[3]);
    agg[(size_t)node * 64 + lane] = pack_bf16(rs.x, rs.y);
}

// ------- hop-2 gather, fp8 PLANE-SPLIT: each phase's table = 3.2 MB (fits per-XCD L2) -------
// plane-major block order => temporal separation; lane loads 1 byte of the 64B plane row
__global__ __launch_bounds__(256) void k_gather8(const uchar* __restrict__ emb8,
                                                 const int* __restrict__ offs,
                                                 const int* __restrict__ csr,
                                                 ushort* __restrict__ agg_us) {
    int plane = (blockIdx.x >= GBLK) ? 1 : 0;
    int blk = blockIdx.x - plane * GBLK;
    int node = (blk * 256 + threadIdx.x) >> 6;
    int lane = threadIdx.x & 63;
    if (node >= N_NODES) return;
    const uchar* base = emb8 + (size_t)plane * PLANESZ;
    int s = offs[node], e = offs[node + 1];
    float a[8] = {0.f};
    for (int cb = s; cb < e; cb += 64) {
        int idx = cb + lane;
        int cv = (idx < e) ? csr[idx] : 0;     // one coalesced load per 64 edges
        int cnt = e - cb; if (cnt > 64) cnt = 64;
        int j = 0;
        for (; j + 8 <= cnt; j += 8) {
            uint32 bt[8];
#pragma unroll
            for (int u = 0; u < 8; u++) {
                int c = __shfl(cv, j + u);
                bt[u] = base[(size_t)c * 64 + lane];
            }
#pragma unroll
            for (int u = 0; u < 8; u++) {
                f32x2 d = __builtin_amdgcn_cvt_pk_f32_fp8((int)bt[u], false);
                a[u] += d.x;   // upper byte is 0 -> d.y == 0
            }
        }
        for (; j < cnt; j++) {
            int c = __shfl(cv, j);
            uint32 b1 = base[(size_t)c * 64 + lane];
            f32x2 d = __builtin_amdgcn_cvt_pk_f32_fp8((int)b1, false);
            a[0] += d.x;
        }
    }
    float r = (((a[0] + a[1]) + (a[2] + a[3])) + ((a[4] + a[5]) + (a[6] + a[7]))) * 64.f;
    agg_us[(size_t)node * 128 + plane * 64 + lane] = (ushort)bf16r(r);
}

#define LROW 136  // padded LDS row, bf16 elems

// ------- MFMA GEMM hop: emb = relu(agg @ W2T + x*w1 + ea*v3) -------
// !LAST: emit fp8 planes (scale 2^-6). LAST: emit bf16 emb + fused W7-head.
template <bool LAST>
__global__ __launch_bounds__(256) void k_gemm(const uint32* __restrict__ agg,   // bf16 [N][64u32]
                                              const ushort* __restrict__ w2p,   // B-frag packed
                                              const float* __restrict__ w1l,
                                              const float* __restrict__ v3l,
                                              const float* __restrict__ x,
                                              const float* __restrict__ ea_sum,
                                              uint32* __restrict__ embOut,      // bf16 (LAST)
                                              uchar* __restrict__ emb8Out,      // fp8 planes (!LAST)
                                              const ushort* __restrict__ w7p,
                                              const float* __restrict__ W5,
                                              float* __restrict__ outp) {
    __shared__ ushort tile[64 * LROW]; // 17408 B
    int tid = threadIdx.x;
    int tbase = blockIdx.x * 64;
    {
        const uint2* src = (const uint2*)(agg + (size_t)tbase * 64);
        int vn = N_NODES - tbase; if (vn > 64) vn = 64;
        int lim = vn * 32;
        for (int i = tid; i < 64 * 32; i += 256) {
            uint2 u = (i < lim) ? src[i] : make_uint2(0u, 0u);
            int r = i >> 5, c4 = (i & 31) * 4;
            *(uint2*)&tile[r * LROW + c4] = u;
        }
    }
    __syncthreads();
    int wv = tid >> 6, lane = tid & 63;
    int n0 = lane & 15, quad = lane >> 4;
    int arow = wv * 16 + n0;
    bf16x8 a0 = *(const bf16x8*)&tile[arow * LROW + 0 * 32 + quad * 8];
    bf16x8 a1 = *(const bf16x8*)&tile[arow * LROW + 1 * 32 + quad * 8];
    bf16x8 a2 = *(const bf16x8*)&tile[arow * LROW + 2 * 32 + quad * 8];
    bf16x8 a3 = *(const bf16x8*)&tile[arow * LROW + 3 * 32 + quad * 8];
    const bf16x8* wb = (const bf16x8*)w2p;
    f32x4 acc[8];
#pragma unroll
    for (int t = 0; t < 8; t++) {
        f32x4 c = {0.f, 0.f, 0.f, 0.f};
        c = __builtin_amdgcn_mfma_f32_16x16x32_bf16(a0, wb[(t * 4 + 0) * 64 + lane], c, 0, 0, 0);
        c = __builtin_amdgcn_mfma_f32_16x16x32_bf16(a1, wb[(t * 4 + 1) * 64 + lane], c, 0, 0, 0);
        c = __builtin_amdgcn_mfma_f32_16x16x32_bf16(a2, wb[(t * 4 + 2) * 64 + lane], c, 0, 0, 0);
        c = __builtin_amdgcn_mfma_f32_16x16x32_bf16(a3, wb[(t * 4 + 3) * 64 + lane], c, 0, 0, 0);
        acc[t] = c;
    }
    float xs[4], es[4];
#pragma unroll
    for (int r = 0; r < 4; r++) {
        int n = tbase + wv * 16 + quad * 4 + r;
        xs[r] = (n < N_NODES) ? x[n] : 0.f;
        es[r] = (n < N_NODES) ? ea_sum[n] : 0.f;
    }
    if (!LAST) {
        // epilogue: fp8 output, scale 2^-6 (exact pow2; rescaled x64 in k_gather8)
        uchar* stile = (uchar*)tile;   // rows stride 136 B; wave-private rows
#pragma unroll
        for (int t = 0; t < 8; t++) {
            int hp = t * 16 + n0;
            float w1v = w1l[hp], v3v = v3l[hp];
#pragma unroll
            for (int r = 0; r < 4; r++) {
                float v = fmaxf(acc[t][r] + xs[r] * w1v + es[r] * v3v, 0.f) * 0.015625f;
                int enc = __builtin_amdgcn_cvt_pk_fp8_f32(v, v, 0, false);
                stile[(wv * 16 + quad * 4 + r) * 136 + hp] = (uchar)(enc & 0xff);
            }
        }
        __syncthreads();
        int vn = N_NODES - tbase; if (vn > 64) vn = 64;
        for (int i = tid; i < 64 * 32; i += 256) {
            int r = i >> 5, c4 = (i & 31) * 4;
            if (r < vn) {
                uint32 u = *(const uint32*)&stile[r * 136 + c4];
                int plane = c4 >> 6;
                *(uint32*)(emb8Out + (size_t)plane * PLANESZ +
                           (size_t)(tbase + r) * 64 + (c4 & 63)) = u;
            }
        }
    } else {
        // epilogue: bf16 output back through LDS + fused W7 head
#pragma unroll
        for (int t = 0; t < 8; t++) {
            int hp = t * 16 + n0;
            float w1v = w1l[hp], v3v = v3l[hp];
#pragma unroll
            for (int r = 0; r < 4; r++) {
                float v = fmaxf(acc[t][r] + xs[r] * w1v + es[r] * v3v, 0.f);
                tile[(wv * 16 + quad * 4 + r) * LROW + hp] = (ushort)bf16r(v);
            }
        }
        __syncthreads();
        {
            int vn = N_NODES - tbase; if (vn > 64) vn = 64;
            for (int i = tid; i < 64 * 32; i += 256) {
                int r = i >> 5, c4 = (i & 31) * 4;
                if (r < vn) {
                    uint2 u = *(const uint2*)&tile[r * LROW + c4];
                    *(uint2*)(embOut + (size_t)(tbase + r) * 64 + (size_t)(i & 31) * 2) = u;
                }
            }
        }
        bf16x8 b0 = *(const bf16x8*)&tile[arow * LROW + 0 * 32 + quad * 8];
        bf16x8 b1 = *(const bf16x8*)&tile[arow * LROW + 1 * 32 + quad * 8];
        bf16x8 b2 = *(const bf16x8*)&tile[arow * LROW + 2 * 32 + quad * 8];
        bf16x8 b3 = *(const bf16x8*)&tile[arow * LROW + 3 * 32 + quad * 8];
        const bf16x8* w7 = (const bf16x8*)w7p;
        float p[4] = {0.f, 0.f, 0.f, 0.f};
#pragma unroll
        for (int t = 0; t < 8; t++) {
            f32x4 c = {0.f, 0.f, 0.f, 0.f};
            c = __builtin_amdgcn_mfma_f32_16x16x32_bf16(b0, w7[(t * 4 + 0) * 64 + lane], c, 0, 0, 0);
            c = __builtin_amdgcn_mfma_f32_16x16x32_bf16(b1, w7[(t * 4 + 1) * 64 + lane], c, 0, 0, 0);
            c = __builtin_amdgcn_mfma_f32_16x16x32_bf16(b2, w7[(t * 4 + 2) * 64 + lane], c, 0, 0, 0);
            c = __builtin_amdgcn_mfma_f32_16x16x32_bf16(b3, w7[(t * 4 + 3) * 64 + lane], c, 0, 0, 0);
            float w5v = W5[128 + t * 16 + n0];
#pragma unroll
            for (int r = 0; r < 4; r++) p[r] += fmaxf(c[r], 0.f) * w5v;
        }
#pragma unroll
        for (int r = 0; r < 4; r++) {
            float v = p[r];
            v += __shfl_xor(v, 1);
            v += __shfl_xor(v, 2);
            v += __shfl_xor(v, 4);
            v += __shfl_xor(v, 8);
            int n = tbase + wv * 16 + quad * 4 + r;
            if (n0 == 0 && n < N_NODES) outp[n] = v;
        }
    }
}

// ------- pooling (fused s_g): 256 blocks; last block computes s_g = relu(pooled@W6T).W5[:128] -------
__global__ __launch_bounds__(256) void k_pool2(const uint32* __restrict__ emb,
                                               const int* __restrict__ gstart,
                                               float* __restrict__ pooled,
                                               int* __restrict__ done,
                                               const float* __restrict__ W6,
                                               const float* __restrict__ W5,
                                               float* __restrict__ s_g) {
    __shared__ float2 red[4][64];
    __shared__ int lastflag;
    int bid = blockIdx.x;
    int g = bid >> 4, chunk = bid & 15;
    int gs = gstart[g], ge = gstart[g + 1];
    int len = ge - gs;
    int cs = gs + (int)(((long long)len * chunk) >> 4);
    int ce = gs + (int)(((long long)len * (chunk + 1)) >> 4);
    int sub = threadIdx.x >> 6, lane = threadIdx.x & 63;
    float ax = 0.f, ay = 0.f;
    for (int n = cs + sub; n < ce; n += 4) {
        uint32 u = emb[(size_t)n * 64 + lane];
        ax += bf_lo(u); ay += bf_hi(u);
    }
    red[sub][lane] = make_float2(ax, ay);
    __syncthreads();
    if (sub == 0) {
        float2 r0 = red[0][lane], r1 = red[1][lane], r2 = red[2][lane], r3 = red[3][lane];
        atomicAdd(&pooled[g * HID + 2 * lane],     (r0.x + r1.x) + (r2.x + r3.x));
        atomicAdd(&pooled[g * HID + 2 * lane + 1], (r0.y + r1.y) + (r2.y + r3.y));
    }
    if (threadIdx.x == 0) {
        __threadfence();
        int old = atomicAdd(done, 1);
        lastflag = (old == (int)gridDim.x - 1);
    }
    __syncthreads();
    if (lastflag) {
        __shared__ float pool_s[NGRAPH * HID]; // 8 KB
        __shared__ float red2[NGRAPH * HID];   // 8 KB
        int tid = threadIdx.x;
        for (int i = tid; i < NGRAPH * HID; i += 256)
            pool_s[i] = atomicAdd(&pooled[i], 0.f);   // coherent read
        __syncthreads();
        if (tid < HID) {
            int hp = tid;
            float acc[NGRAPH];
#pragma unroll
            for (int gg = 0; gg < NGRAPH; gg++) acc[gg] = 0.f;
            for (int h = 0; h < HID; h++) {
                float wv = W6[hp * HID + h];
#pragma unroll
                for (int gg = 0; gg < NGRAPH; gg++)
                    acc[gg] += pool_s[gg * HID + h] * wv;
            }
            float w5v = W5[hp];
#pragma unroll
            for (int gg = 0; gg < NGRAPH; gg++)
                red2[gg * HID + hp] = fmaxf(acc[gg], 0.f) * w5v;
        }
        __syncthreads();
        if (tid < NGRAPH) {
            float s = 0.f;
            for (int h = 0; h < HID; h++) s += red2[tid * HID + h];
            s_g[tid] = s;
        }
    }
}

// ---------------- final add: out[n] += s_g[batch[n]] + b5 ----------------
__global__ __launch_bounds__(256) void k_addsg(float* __restrict__ out,
                                               const int* __restrict__ batch,
                                               const float* __restrict__ s_g,
                                               const float* __restrict__ b5) {
    int n = blockIdx.x * 256 + threadIdx.x;
    if (n < N_NODES) out[n] += s_g[batch[n]] + b5[0];
}

extern "C" void kernel_launch(void* const* d_in, const int* in_sizes, int n_in,
                              void* d_out, int out_size, void* d_ws, size_t ws_size,
                              hipStream_t stream) {
    (void)in_sizes; (void)n_in; (void)out_size; (void)ws_size;
    const float* x    = (const float*)d_in[0];
    const int*   ei   = (const int*)d_in[1];   // [2,E] flat: row then col
    const float* ea   = (const float*)d_in[2];
    const int*   bat  = (const int*)d_in[3];
    const float* W1   = (const float*)d_in[4]; // [3,128,1]
    const float* W2   = (const float*)d_in[5]; // [3,128,128]
    const float* W3   = (const float*)d_in[6];
    const float* W4   = (const float*)d_in[7]; // [3,128,1]
    const float* W5   = (const float*)d_in[8]; // [1,256]
    const float* b5   = (const float*)d_in[9];
    const float* W6   = (const float*)d_in[10];
    const float* W7   = (const float*)d_in[11];
    float* out = (float*)d_out;

    const int* row = ei;
    const int* col = ei + N_EDGES;

    // workspace layout (4B elems)
    float* wsf = (float*)d_ws;
    int*   wsi = (int*)d_ws;
    size_t o = 0;
    float* pooled = wsf + o; o += NGRAPH * HID;     // zeroed (atomic targets)
    float* s_g    = wsf + o; o += NGRAPH;           // zeroed
    int*   done_p2   = wsi + o; o += 1;             // zeroed arrival counters
    int*   done_pool = wsi + o; o += 1;
    size_t ztot = o;
    int*   offs   = wsi + o; o += N_NODES + 1;
    float* ea_sum = wsf + o; o += N_NODES;
    int*   gstart = wsi + o; o += NGRAPH + 1;
    int*   btot   = wsi + o; o += NB;
    int*   bbase  = wsi + o; o += NB + 1;
    float* v3     = wsf + o; o += 3 * HID;
    int*   blkh   = wsi + o; o += NB * NBLK;
    o = (o + 1) & ~(size_t)1;
    float2* pxe   = (float2*)(wsi + o); o += 2 * (size_t)N_NODES;
    o = (o + 3) & ~(size_t)3;
    ushort* wpack = (ushort*)(wsi + o); o += 4 * 16384 / 2;
    int*    csr   = wsi + o; o += N_EDGES;
    o = (o + 1) & ~(size_t)1;
    int2*   pea   = (int2*)(wsi + o); o += 2 * (size_t)N_EDGES;
    float2* pxec  = (float2*)(wsi + o); o += 2 * (size_t)N_EDGES;
    o = (o + 1) & ~(size_t)1;
    uint32* embA  = (uint32*)(wsi + o); o += (size_t)N_NODES * 64;  // bf16 [N][128]
    uchar*  emb8  = (uchar*)(wsi + o);  o += (size_t)N_NODES * 32;  // fp8 2 planes [N][64]
    uint32* aggB  = (uint32*)(wsi + o); o += (size_t)N_NODES * 64;  // bf16 [N][128]

    const ushort* w2p1 = wpack + 1 * 16384;
    const ushort* w2p2 = wpack + 2 * 16384;
    const ushort* w7p  = wpack + 3 * 16384;

    // 0) init: zero accumulators/counters + graph bounds + weight pack + v3 (fused)
    k_init<<<256, 256, 0, stream>>>((float*)d_ws, (int)ztot, bat, gstart,
                                    W2, W7, W3, W4, (ushort*)wpack, v3);
    // 1) atomic-free CSR build + CSR-ordered hop-1 payload
    k_p1_hist<<<NBLK, 1024, 0, stream>>>(row, blkh);
    k_p2<<<NB, NBLK, 0, stream>>>(blkh, btot, bbase, done_p2);
    k_p3_part<<<NBLK, 1024, 0, stream>>>(row, col, ea, blkh, bbase, pea);
    k_p4a<<<NB, 512, 0, stream>>>(pea, bbase, x, offs, ea_sum, pxe);
    k_p4b<<<NB, 512, 0, stream>>>(pea, bbase, offs, pxe, csr, pxec);
    // 2) hop 1: streaming recompute-gather -> aggB ; MFMA gemm -> fp8 planes
    k_gather1<<<(N_NODES * 64 + 255) / 256, 256, 0, stream>>>(pxec, offs, W1, v3, aggB);
    k_gemm<false><<<(N_NODES + 63) / 64, 256, 0, stream>>>(
        aggB, w2p1, W1 + 1 * HID, v3 + 1 * HID, x, ea_sum, nullptr, emb8, nullptr, nullptr, nullptr);
    // 3) hop 2: plane-split fp8 gather -> aggB ; MFMA gemm + W7 head -> embA, out partial
    k_gather8<<<2 * GBLK, 256, 0, stream>>>(emb8, offs, csr, (ushort*)aggB);
    k_gemm<true><<<(N_NODES + 63) / 64, 256, 0, stream>>>(
        aggB, w2p2, W1 + 2 * HID, v3 + 2 * HID, x, ea_sum, embA, nullptr, w7p, W5, out);
    // 4) graph pooling + fused s_g (last-block)
    k_pool2<<<NGRAPH * 16, 256, 0, stream>>>(embA, gstart, pooled, done_pool, W6, W5, s_g);
    // 5) add graph term + bias
    k_addsg<<<(N_NODES + 255) / 256, 256, 0, stream>>>(out, bat, s_g, b5);
}

// Round 10
// 314.137 us; speedup vs baseline: 1.0101x; 1.0101x over previous
//
#include <hip/hip_runtime.h>
#include <hip/hip_bf16.h>

#define N_NODES 50000
#define N_EDGES 1600000
#define NGRAPH  16
#define HID     128

#define RPB   128                           // rows per bucket
#define NB    ((N_NODES + RPB - 1) / RPB)   // 391 buckets
#define NBLK  256                           // partition blocks
#define EPB   ((N_EDGES + NBLK - 1) / NBLK) // 6250 edges per partition block

typedef unsigned int uint32;
typedef unsigned short ushort;
typedef unsigned char uchar;
typedef __attribute__((ext_vector_type(8))) short bf16x8;
typedef __attribute__((ext_vector_type(4))) float f32x4;
typedef __attribute__((ext_vector_type(2))) float f32x2;

// bf16 round-to-nearest-even helpers
__device__ __forceinline__ uint32 bf16r(float f) {
    uint32 b = __float_as_uint(f);
    return (b + 0x7fffu + ((b >> 16) & 1u)) >> 16;
}
__device__ __forceinline__ uint32 pack_bf16(float lo, float hi) {
    return bf16r(lo) | (bf16r(hi) << 16);
}
__device__ __forceinline__ float bf_lo(uint32 u) { return __uint_as_float(u << 16); }
__device__ __forceinline__ float bf_hi(uint32 u) { return __uint_as_float(u & 0xffff0000u); }

// ------- init (fused): zero accumulators+counters, graph bounds, weight pack, v3 -------
__global__ __launch_bounds__(256) void k_init(float* __restrict__ zp, int zn,
                                              const int* __restrict__ batch,
                                              int* __restrict__ gstart,
                                              const float* __restrict__ W2,
                                              const float* __restrict__ W7,
                                              const float* __restrict__ W3,
                                              const float* __restrict__ W4,
                                              ushort* __restrict__ wpack,
                                              float* __restrict__ v3) {
    int idx = blockIdx.x * 256 + threadIdx.x;
    if (idx < zn) zp[idx] = 0.f;
    if (idx <= NGRAPH) {
        int lo = 0, hi = N_NODES;
        while (lo < hi) {
            int mid = (lo + hi) >> 1;
            if (batch[mid] < idx) lo = mid + 1; else hi = mid;
        }
        gstart[idx] = lo;
    }
    if (idx < 4 * 16384) {
        int m = idx >> 14, f = idx & 16383;
        int j = f & 7, lane = (f >> 3) & 63, kk = (f >> 9) & 3, t = (f >> 11) & 7;
        int hp = t * 16 + (lane & 15);
        int k  = kk * 32 + ((lane >> 4) & 3) * 8 + j;
        const float* src = (m < 3) ? (W2 + m * HID * HID) : W7;
        wpack[idx] = (ushort)bf16r(src[hp * HID + k]);
    }
    if (idx < 3 * HID) {
        int l = idx / HID, hp = idx % HID;
        float acc = 0.f;
        for (int h = 0; h < HID; h++)
            acc += W3[l * HID * HID + hp * HID + h] * fmaxf(W4[l * HID + h], 0.f);
        v3[idx] = acc;
    }
}

// ---------------- P1: per-(bucket,block) histogram ----------------
__global__ __launch_bounds__(1024) void k_p1_hist(const int* __restrict__ row,
                                                  int* __restrict__ blkhist) {
    __shared__ int hist[NB];
    int tid = threadIdx.x, blk = blockIdx.x;
    for (int i = tid; i < NB; i += 1024) hist[i] = 0;
    __syncthreads();
    int s = blk * EPB, e = s + EPB; if (e > N_EDGES) e = N_EDGES;
    for (int i = s + tid; i < e; i += 1024)
        atomicAdd(&hist[row[i] >> 7], 1);
    __syncthreads();
    for (int i = tid; i < NB; i += 1024)
        blkhist[i * NBLK + blk] = hist[i];
}

// ------- P2 (fused): per-bucket scan over NBLK counts; last block scans bucket totals -------
__global__ __launch_bounds__(NBLK) void k_p2(int* __restrict__ blkhist,
                                             int* __restrict__ btot,
                                             int* __restrict__ bbase,
                                             int* __restrict__ done) {
    __shared__ int sums[NBLK];
    __shared__ int lastflag;
    int t = threadIdx.x, b = blockIdx.x;
    int v = blkhist[b * NBLK + t];
    sums[t] = v;
    __syncthreads();
    for (int d = 1; d < NBLK; d <<= 1) {
        int u = (t >= d) ? sums[t - d] : 0;
        __syncthreads();
        sums[t] += u;
        __syncthreads();
    }
    blkhist[b * NBLK + t] = sums[t] - v;     // local exclusive
    if (t == NBLK - 1) btot[b] = sums[t];    // bucket total
    if (t == 0) {
        __threadfence();
        int old = atomicAdd(done, 1);
        lastflag = (old == NB - 1);
    }
    __syncthreads();
    if (lastflag) {
        int i0 = 2 * t, i1 = 2 * t + 1;
        int v0 = (i0 < NB) ? atomicAdd(&btot[i0], 0) : 0;
        int v1 = (i1 < NB) ? atomicAdd(&btot[i1], 0) : 0;
        int sum = v0 + v1;
        sums[t] = sum;
        __syncthreads();
        for (int d = 1; d < NBLK; d <<= 1) {
            int u = (t >= d) ? sums[t - d] : 0;
            __syncthreads();
            sums[t] += u;
            __syncthreads();
        }
        int excl = sums[t] - sum;
        if (i0 < NB) bbase[i0] = excl;
        if (i1 < NB) bbase[i1] = excl + v0;
        if (t == NBLK - 1) bbase[NB] = sums[t]; // == E
    }
}

// ------- P3: scatter int2{rowlocal:8|col:16, ea} into bucket runs (LDS cursors) -------
__global__ __launch_bounds__(1024) void k_p3_part(const int* __restrict__ row,
                                                  const int* __restrict__ col,
                                                  const float* __restrict__ ea,
                                                  const int* __restrict__ blkhist,
                                                  const int* __restrict__ bbase,
                                                  int2* __restrict__ pea) {
    __shared__ int cur[NB];
    int tid = threadIdx.x, blk = blockIdx.x;
    for (int i = tid; i < NB; i += 1024)
        cur[i] = bbase[i] + blkhist[i * NBLK + blk];
    __syncthreads();
    int s = blk * EPB, e = s + EPB; if (e > N_EDGES) e = N_EDGES;
    for (int i = s + tid; i < e; i += 1024) {
        int r = row[i], c = col[i];
        float a = ea[i];
        int slot = atomicAdd(&cur[r >> 7], 1);
        pea[slot] = make_int2(((r & (RPB - 1)) << 16) | c, __float_as_int(a));
    }
}

// ------- P4a: per-bucket counts + ea_sum + local scan -> offs, pxe -------
__global__ __launch_bounds__(512) void k_p4a(const int2* __restrict__ pea,
                                             const int* __restrict__ bbase,
                                             const float* __restrict__ x,
                                             int* __restrict__ offs,
                                             float* __restrict__ ea_sum,
                                             float2* __restrict__ pxe) {
    __shared__ int   cnt[RPB];
    __shared__ float eas[RPB];
    __shared__ int   scan_s[RPB];
    int tid = threadIdx.x, b = blockIdx.x;
    if (tid < RPB) { cnt[tid] = 0; eas[tid] = 0.f; }
    __syncthreads();
    int s = bbase[b], e = bbase[b + 1];
    for (int i = s + tid; i < e; i += 512) {
        int2 p = pea[i];
        int lr = ((uint32)p.x) >> 16;
        atomicAdd(&cnt[lr], 1);
        atomicAdd(&eas[lr], __int_as_float(p.y));
    }
    __syncthreads();
    if (tid < RPB) scan_s[tid] = cnt[tid];
    __syncthreads();
    for (int d = 1; d < RPB; d <<= 1) {
        int v = 0;
        if (tid < RPB && tid >= d) v = scan_s[tid - d];
        __syncthreads();
        if (tid < RPB) scan_s[tid] += v;
        __syncthreads();
    }
    int nbase = b * RPB;
    if (tid < RPB) {
        int excl = scan_s[tid] - cnt[tid];
        int n = nbase + tid;
        if (n < N_NODES) {
            offs[n] = s + excl;
            ea_sum[n] = eas[tid];
            pxe[n] = make_float2(x[n], eas[tid]);
        }
    }
    if (b == NB - 1 && tid == 0) offs[N_NODES] = e;
}

// ------- P4b: scatter csr + CSR-ordered payload pxec[slot] = pxe[col] -------
__global__ __launch_bounds__(512) void k_p4b(const int2* __restrict__ pea,
                                             const int* __restrict__ bbase,
                                             const int* __restrict__ offs,
                                             const float2* __restrict__ pxe,
                                             int* __restrict__ csr,
                                             float2* __restrict__ pxec) {
    __shared__ int cur[RPB];
    int tid = threadIdx.x, b = blockIdx.x;
    int nbase = b * RPB;
    if (tid < RPB) cur[tid] = (nbase + tid < N_NODES) ? offs[nbase + tid] : 0;
    __syncthreads();
    int s = bbase[b], e = bbase[b + 1];
    for (int i = s + tid; i < e; i += 512) {
        int2 p = pea[i];
        int c = p.x & 0xFFFF;
        int slot = atomicAdd(&cur[((uint32)p.x) >> 16], 1);
        csr[slot] = c;
        pxec[slot] = pxe[c];   // 400 KB table, L2-resident
    }
}

// ------- hop-1 gather by recompute, streaming CSR-ordered payload (no indirection) -------
__global__ __launch_bounds__(256) void k_gather1(const float2* __restrict__ pxec,
                                                 const int* __restrict__ offs,
                                                 const float* __restrict__ w1,
                                                 const float* __restrict__ v3,
                                                 uint32* __restrict__ agg) {
    int node = (blockIdx.x * 256 + threadIdx.x) >> 6;
    int lane = threadIdx.x & 63;
    if (node >= N_NODES) return;
    f32x2 w1v = {w1[2 * lane], w1[2 * lane + 1]};
    f32x2 v3v = {v3[2 * lane], v3[2 * lane + 1]};
    const f32x2 zero = {0.f, 0.f};
    int s = offs[node], e = offs[node + 1];
    f32x2 acc[4] = {zero, zero, zero, zero};
    int j = s;
    for (; j + 8 <= e; j += 8) {
        float2 p[8];
#pragma unroll
        for (int u = 0; u < 8; u++) p[u] = pxec[j + u];   // broadcast, contiguous
#pragma unroll
        for (int u = 0; u < 8; u++) {
            f32x2 px = {p[u].x, p[u].x};
            f32x2 pe = {p[u].y, p[u].y};
            f32x2 r = __builtin_elementwise_fma(px, w1v, pe * v3v);
            acc[u & 3] += __builtin_elementwise_max(r, zero);
        }
    }
    for (; j < e; j++) {
        float2 p = pxec[j];
        f32x2 px = {p.x, p.x};
        f32x2 pe = {p.y, p.y};
        f32x2 r = __builtin_elementwise_fma(px, w1v, pe * v3v);
        acc[0] += __builtin_elementwise_max(r, zero);
    }
    f32x2 rs = (acc[0] + acc[1]) + (acc[2] + acc[3]);
    agg[(size_t)node * 64 + lane] = pack_bf16(rs.x, rs.y);
}

// ------- hop-2 gather over fp8 emb rows (128 B): coalesced csr + shfl; 16-deep MLP -------
__global__ __launch_bounds__(256) void k_gather(const uchar* __restrict__ emb8,
                                                const int* __restrict__ offs,
                                                const int* __restrict__ csr,
                                                uint32* __restrict__ agg) {
    int node = (blockIdx.x * 256 + threadIdx.x) >> 6;
    int lane = threadIdx.x & 63;
    if (node >= N_NODES) return;
    int s = offs[node], e = offs[node + 1];
    float ax[8] = {0.f}, ay[8] = {0.f};
    for (int base = s; base < e; base += 64) {
        int idx = base + lane;
        int cv = (idx < e) ? csr[idx] : 0;     // one coalesced load per 64 edges
        int cnt = e - base; if (cnt > 64) cnt = 64;
        int j = 0;
        for (; j + 16 <= cnt; j += 16) {
            int h16[16];
#pragma unroll
            for (int u = 0; u < 16; u++) {
                int c = __shfl(cv, j + u);
                h16[u] = *(const ushort*)(emb8 + (size_t)c * 128 + 2 * lane);
            }
#pragma unroll
            for (int u = 0; u < 16; u++) {
                f32x2 d = __builtin_amdgcn_cvt_pk_f32_fp8(h16[u], false);
                ax[u & 7] += d.x; ay[u & 7] += d.y;
            }
        }
        for (; j < cnt; j++) {
            int c = __shfl(cv, j);
            int h = *(const ushort*)(emb8 + (size_t)c * 128 + 2 * lane);
            f32x2 d = __builtin_amdgcn_cvt_pk_f32_fp8(h, false);
            ax[0] += d.x; ay[0] += d.y;
        }
    }
    float rx = (((ax[0] + ax[1]) + (ax[2] + ax[3])) + ((ax[4] + ax[5]) + (ax[6] + ax[7]))) * 64.f;
    float ry = (((ay[0] + ay[1]) + (ay[2] + ay[3])) + ((ay[4] + ay[5]) + (ay[6] + ay[7]))) * 64.f;
    agg[(size_t)node * 64 + lane] = pack_bf16(rx, ry);
}

#define LROW 136  // padded LDS row, bf16 elems

// ------- MFMA GEMM hop: emb = relu(agg @ W2T + x*w1 + ea*v3) -------
// !LAST: emit fp8 emb (scale 2^-6, row 128 B). LAST: emit bf16 emb + fused W7-head.
template <bool LAST>
__global__ __launch_bounds__(256) void k_gemm(const uint32* __restrict__ agg,   // bf16 [N][64u32]
                                              const ushort* __restrict__ w2p,   // B-frag packed
                                              const float* __restrict__ w1l,
                                              const float* __restrict__ v3l,
                                              const float* __restrict__ x,
                                              const float* __restrict__ ea_sum,
                                              uint32* __restrict__ embOut,      // bf16 (LAST)
                                              uchar* __restrict__ emb8Out,      // fp8 (!LAST)
                                              const ushort* __restrict__ w7p,
                                              const float* __restrict__ W5,
                                              float* __restrict__ outp) {
    __shared__ ushort tile[64 * LROW]; // 17408 B
    int tid = threadIdx.x;
    int tbase = blockIdx.x * 64;
    {
        const uint2* src = (const uint2*)(agg + (size_t)tbase * 64);
        int vn = N_NODES - tbase; if (vn > 64) vn = 64;
        int lim = vn * 32;
        for (int i = tid; i < 64 * 32; i += 256) {
            uint2 u = (i < lim) ? src[i] : make_uint2(0u, 0u);
            int r = i >> 5, c4 = (i & 31) * 4;
            *(uint2*)&tile[r * LROW + c4] = u;
        }
    }
    __syncthreads();
    int wv = tid >> 6, lane = tid & 63;
    int n0 = lane & 15, quad = lane >> 4;
    int arow = wv * 16 + n0;
    bf16x8 a0 = *(const bf16x8*)&tile[arow * LROW + 0 * 32 + quad * 8];
    bf16x8 a1 = *(const bf16x8*)&tile[arow * LROW + 1 * 32 + quad * 8];
    bf16x8 a2 = *(const bf16x8*)&tile[arow * LROW + 2 * 32 + quad * 8];
    bf16x8 a3 = *(const bf16x8*)&tile[arow * LROW + 3 * 32 + quad * 8];
    const bf16x8* wb = (const bf16x8*)w2p;
    f32x4 acc[8];
#pragma unroll
    for (int t = 0; t < 8; t++) {
        f32x4 c = {0.f, 0.f, 0.f, 0.f};
        c = __builtin_amdgcn_mfma_f32_16x16x32_bf16(a0, wb[(t * 4 + 0) * 64 + lane], c, 0, 0, 0);
        c = __builtin_amdgcn_mfma_f32_16x16x32_bf16(a1, wb[(t * 4 + 1) * 64 + lane], c, 0, 0, 0);
        c = __builtin_amdgcn_mfma_f32_16x16x32_bf16(a2, wb[(t * 4 + 2) * 64 + lane], c, 0, 0, 0);
        c = __builtin_amdgcn_mfma_f32_16x16x32_bf16(a3, wb[(t * 4 + 3) * 64 + lane], c, 0, 0, 0);
        acc[t] = c;
    }
    float xs[4], es[4];
#pragma unroll
    for (int r = 0; r < 4; r++) {
        int n = tbase + wv * 16 + quad * 4 + r;
        xs[r] = (n < N_NODES) ? x[n] : 0.f;
        es[r] = (n < N_NODES) ? ea_sum[n] : 0.f;
    }
    if (!LAST) {
        // epilogue: fp8 output, scale 2^-6 (exact pow2; rescaled x64 in k_gather)
        uchar* stile = (uchar*)tile;   // rows stride 136 B; wave-private rows
#pragma unroll
        for (int t = 0; t < 8; t++) {
            int hp = t * 16 + n0;
            float w1v = w1l[hp], v3v = v3l[hp];
#pragma unroll
            for (int r = 0; r < 4; r++) {
                float v = fmaxf(acc[t][r] + xs[r] * w1v + es[r] * v3v, 0.f) * 0.015625f;
                int enc = __builtin_amdgcn_cvt_pk_fp8_f32(v, v, 0, false);
                stile[(wv * 16 + quad * 4 + r) * 136 + hp] = (uchar)(enc & 0xff);
            }
        }
        __syncthreads();
        int vn = N_NODES - tbase; if (vn > 64) vn = 64;
        for (int i = tid; i < 64 * 32; i += 256) {
            int r = i >> 5, c4 = (i & 31) * 4;
            if (r < vn) {
                uint32 u = *(const uint32*)&stile[r * 136 + c4];
                *(uint32*)(emb8Out + (size_t)(tbase + r) * 128 + c4) = u;
            }
        }
    } else {
        // epilogue: bf16 output back through LDS + fused W7 head
#pragma unroll
        for (int t = 0; t < 8; t++) {
            int hp = t * 16 + n0;
            float w1v = w1l[hp], v3v = v3l[hp];
#pragma unroll
            for (int r = 0; r < 4; r++) {
                float v = fmaxf(acc[t][r] + xs[r] * w1v + es[r] * v3v, 0.f);
                tile[(wv * 16 + quad * 4 + r) * LROW + hp] = (ushort)bf16r(v);
            }
        }
        __syncthreads();
        {
            int vn = N_NODES - tbase; if (vn > 64) vn = 64;
            for (int i = tid; i < 64 * 32; i += 256) {
                int r = i >> 5, c4 = (i & 31) * 4;
                if (r < vn) {
                    uint2 u = *(const uint2*)&tile[r * LROW + c4];
                    *(uint2*)(embOut + (size_t)(tbase + r) * 64 + (size_t)(i & 31) * 2) = u;
                }
            }
        }
        bf16x8 b0 = *(const bf16x8*)&tile[arow * LROW + 0 * 32 + quad * 8];
        bf16x8 b1 = *(const bf16x8*)&tile[arow * LROW + 1 * 32 + quad * 8];
        bf16x8 b2 = *(const bf16x8*)&tile[arow * LROW + 2 * 32 + quad * 8];
        bf16x8 b3 = *(const bf16x8*)&tile[arow * LROW + 3 * 32 + quad * 8];
        const bf16x8* w7 = (const bf16x8*)w7p;
        float p[4] = {0.f, 0.f, 0.f, 0.f};
#pragma unroll
        for (int t = 0; t < 8; t++) {
            f32x4 c = {0.f, 0.f, 0.f, 0.f};
            c = __builtin_amdgcn_mfma_f32_16x16x32_bf16(b0, w7[(t * 4 + 0) * 64 + lane], c, 0, 0, 0);
            c = __builtin_amdgcn_mfma_f32_16x16x32_bf16(b1, w7[(t * 4 + 1) * 64 + lane], c, 0, 0, 0);
            c = __builtin_amdgcn_mfma_f32_16x16x32_bf16(b2, w7[(t * 4 + 2) * 64 + lane], c, 0, 0, 0);
            c = __builtin_amdgcn_mfma_f32_16x16x32_bf16(b3, w7[(t * 4 + 3) * 64 + lane], c, 0, 0, 0);
            float w5v = W5[128 + t * 16 + n0];
#pragma unroll
            for (int r = 0; r < 4; r++) p[r] += fmaxf(c[r], 0.f) * w5v;
        }
#pragma unroll
        for (int r = 0; r < 4; r++) {
            float v = p[r];
            v += __shfl_xor(v, 1);
            v += __shfl_xor(v, 2);
            v += __shfl_xor(v, 4);
            v += __shfl_xor(v, 8);
            int n = tbase + wv * 16 + quad * 4 + r;
            if (n0 == 0 && n < N_NODES) outp[n] = v;
        }
    }
}

// ------- pooling (fused s_g): 256 blocks; last block computes s_g = relu(pooled@W6T).W5[:128] -------
__global__ __launch_bounds__(256) void k_pool2(const uint32* __restrict__ emb,
                                               const int* __restrict__ gstart,
                                               float* __restrict__ pooled,
                                               int* __restrict__ done,
                                               const float* __restrict__ W6,
                                               const float* __restrict__ W5,
                                               float* __restrict__ s_g) {
    __shared__ float2 red[4][64];
    __shared__ int lastflag;
    int bid = blockIdx.x;
    int g = bid >> 4, chunk = bid & 15;
    int gs = gstart[g], ge = gstart[g + 1];
    int len = ge - gs;
    int cs = gs + (int)(((long long)len * chunk) >> 4);
    int ce = gs + (int)(((long long)len * (chunk + 1)) >> 4);
    int sub = threadIdx.x >> 6, lane = threadIdx.x & 63;
    float ax = 0.f, ay = 0.f;
    for (int n = cs + sub; n < ce; n += 4) {
        uint32 u = emb[(size_t)n * 64 + lane];
        ax += bf_lo(u); ay += bf_hi(u);
    }
    red[sub][lane] = make_float2(ax, ay);
    __syncthreads();
    if (sub == 0) {
        float2 r0 = red[0][lane], r1 = red[1][lane], r2 = red[2][lane], r3 = red[3][lane];
        atomicAdd(&pooled[g * HID + 2 * lane],     (r0.x + r1.x) + (r2.x + r3.x));
        atomicAdd(&pooled[g * HID + 2 * lane + 1], (r0.y + r1.y) + (r2.y + r3.y));
    }
    if (threadIdx.x == 0) {
        __threadfence();
        int old = atomicAdd(done, 1);
        lastflag = (old == (int)gridDim.x - 1);
    }
    __syncthreads();
    if (lastflag) {
        __shared__ float pool_s[NGRAPH * HID]; // 8 KB
        __shared__ float red2[NGRAPH * HID];   // 8 KB
        int tid = threadIdx.x;
        for (int i = tid; i < NGRAPH * HID; i += 256)
            pool_s[i] = atomicAdd(&pooled[i], 0.f);   // coherent read
        __syncthreads();
        if (tid < HID) {
            int hp = tid;
            float acc[NGRAPH];
#pragma unroll
            for (int gg = 0; gg < NGRAPH; gg++) acc[gg] = 0.f;
            for (int h = 0; h < HID; h++) {
                float wv = W6[hp * HID + h];
#pragma unroll
                for (int gg = 0; gg < NGRAPH; gg++)
                    acc[gg] += pool_s[gg * HID + h] * wv;
            }
            float w5v = W5[hp];
#pragma unroll
            for (int gg = 0; gg < NGRAPH; gg++)
                red2[gg * HID + hp] = fmaxf(acc[gg], 0.f) * w5v;
        }
        __syncthreads();
        if (tid < NGRAPH) {
            float s = 0.f;
            for (int h = 0; h < HID; h++) s += red2[tid * HID + h];
            s_g[tid] = s;
        }
    }
}

// ---------------- final add: out[n] += s_g[batch[n]] + b5 ----------------
__global__ __launch_bounds__(256) void k_addsg(float* __restrict__ out,
                                               const int* __restrict__ batch,
                                               const float* __restrict__ s_g,
                                               const float* __restrict__ b5) {
    int n = blockIdx.x * 256 + threadIdx.x;
    if (n < N_NODES) out[n] += s_g[batch[n]] + b5[0];
}

extern "C" void kernel_launch(void* const* d_in, const int* in_sizes, int n_in,
                              void* d_out, int out_size, void* d_ws, size_t ws_size,
                              hipStream_t stream) {
    (void)in_sizes; (void)n_in; (void)out_size; (void)ws_size;
    const float* x    = (const float*)d_in[0];
    const int*   ei   = (const int*)d_in[1];   // [2,E] flat: row then col
    const float* ea   = (const float*)d_in[2];
    const int*   bat  = (const int*)d_in[3];
    const float* W1   = (const float*)d_in[4]; // [3,128,1]
    const float* W2   = (const float*)d_in[5]; // [3,128,128]
    const float* W3   = (const float*)d_in[6];
    const float* W4   = (const float*)d_in[7]; // [3,128,1]
    const float* W5   = (const float*)d_in[8]; // [1,256]
    const float* b5   = (const float*)d_in[9];
    const float* W6   = (const float*)d_in[10];
    const float* W7   = (const float*)d_in[11];
    float* out = (float*)d_out;

    const int* row = ei;
    const int* col = ei + N_EDGES;

    // workspace layout (4B elems)
    float* wsf = (float*)d_ws;
    int*   wsi = (int*)d_ws;
    size_t o = 0;
    float* pooled = wsf + o; o += NGRAPH * HID;     // zeroed (atomic targets)
    float* s_g    = wsf + o; o += NGRAPH;           // zeroed
    int*   done_p2   = wsi + o; o += 1;             // zeroed arrival counters
    int*   done_pool = wsi + o; o += 1;
    size_t ztot = o;
    int*   offs   = wsi + o; o += N_NODES + 1;
    float* ea_sum = wsf + o; o += N_NODES;
    int*   gstart = wsi + o; o += NGRAPH + 1;
    int*   btot   = wsi + o; o += NB;
    int*   bbase  = wsi + o; o += NB + 1;
    float* v3     = wsf + o; o += 3 * HID;
    int*   blkh   = wsi + o; o += NB * NBLK;
    o = (o + 1) & ~(size_t)1;
    float2* pxe   = (float2*)(wsi + o); o += 2 * (size_t)N_NODES;
    o = (o + 3) & ~(size_t)3;
    ushort* wpack = (ushort*)(wsi + o); o += 4 * 16384 / 2;
    int*    csr   = wsi + o; o += N_EDGES;
    o = (o + 1) & ~(size_t)1;
    int2*   pea   = (int2*)(wsi + o); o += 2 * (size_t)N_EDGES;
    float2* pxec  = (float2*)(wsi + o); o += 2 * (size_t)N_EDGES;
    o = (o + 1) & ~(size_t)1;
    uint32* embA  = (uint32*)(wsi + o); o += (size_t)N_NODES * 64;  // bf16 [N][128]
    uchar*  emb8  = (uchar*)(wsi + o);  o += (size_t)N_NODES * 32;  // fp8 [N][128]
    uint32* aggB  = (uint32*)(wsi + o); o += (size_t)N_NODES * 64;  // bf16 [N][128]

    const ushort* w2p1 = wpack + 1 * 16384;
    const ushort* w2p2 = wpack + 2 * 16384;
    const ushort* w7p  = wpack + 3 * 16384;

    // 0) init: zero accumulators/counters + graph bounds + weight pack + v3 (fused)
    k_init<<<256, 256, 0, stream>>>((float*)d_ws, (int)ztot, bat, gstart,
                                    W2, W7, W3, W4, (ushort*)wpack, v3);
    // 1) atomic-free CSR build + CSR-ordered hop-1 payload
    k_p1_hist<<<NBLK, 1024, 0, stream>>>(row, blkh);
    k_p2<<<NB, NBLK, 0, stream>>>(blkh, btot, bbase, done_p2);
    k_p3_part<<<NBLK, 1024, 0, stream>>>(row, col, ea, blkh, bbase, pea);
    k_p4a<<<NB, 512, 0, stream>>>(pea, bbase, x, offs, ea_sum, pxe);
    k_p4b<<<NB, 512, 0, stream>>>(pea, bbase, offs, pxe, csr, pxec);
    // 2) hop 1: streaming recompute-gather -> aggB ; MFMA gemm -> fp8 emb
    k_gather1<<<(N_NODES * 64 + 255) / 256, 256, 0, stream>>>(pxec, offs, W1, v3, aggB);
    k_gemm<false><<<(N_NODES + 63) / 64, 256, 0, stream>>>(
        aggB, w2p1, W1 + 1 * HID, v3 + 1 * HID, x, ea_sum, nullptr, emb8, nullptr, nullptr, nullptr);
    // 3) hop 2: fp8 gather -> aggB ; MFMA gemm + W7 head -> embA, out partial
    k_gather<<<(N_NODES * 64 + 255) / 256, 256, 0, stream>>>(emb8, offs, csr, aggB);
    k_gemm<true><<<(N_NODES + 63) / 64, 256, 0, stream>>>(
        aggB, w2p2, W1 + 2 * HID, v3 + 2 * HID, x, ea_sum, embA, nullptr, w7p, W5, out);
    // 4) graph pooling + fused s_g (last-block)
    k_pool2<<<NGRAPH * 16, 256, 0, stream>>>(embA, gstart, pooled, done_pool, W6, W5, s_g);
    // 5) add graph term + bias
    k_addsg<<<(N_NODES + 255) / 256, 256, 0, stream>>>(out, bat, s_g, b5);
}

// Round 11
// 293.079 us; speedup vs baseline: 1.0827x; 1.0718x over previous
//
#include <hip/hip_runtime.h>
#include <hip/hip_bf16.h>

#define N_NODES 50000
#define N_EDGES 1600000
#define NGRAPH  16
#define HID     128

#define RPB   128                           // rows per bucket
#define NB    ((N_NODES + RPB - 1) / RPB)   // 391 buckets
#define NBLK  256                           // partition blocks
#define EPB   ((N_EDGES + NBLK - 1) / NBLK) // 6250 edges per partition block

typedef unsigned int uint32;
typedef unsigned short ushort;
typedef unsigned char uchar;
typedef __attribute__((ext_vector_type(8))) short bf16x8;
typedef __attribute__((ext_vector_type(4))) float f32x4;
typedef __attribute__((ext_vector_type(2))) float f32x2;

// bf16 round-to-nearest-even helpers
__device__ __forceinline__ uint32 bf16r(float f) {
    uint32 b = __float_as_uint(f);
    return (b + 0x7fffu + ((b >> 16) & 1u)) >> 16;
}
__device__ __forceinline__ uint32 pack_bf16(float lo, float hi) {
    return bf16r(lo) | (bf16r(hi) << 16);
}
__device__ __forceinline__ float bf_lo(uint32 u) { return __uint_as_float(u << 16); }
__device__ __forceinline__ float bf_hi(uint32 u) { return __uint_as_float(u & 0xffff0000u); }

// ------- init (fused): zero accumulators+counters, graph bounds, weight pack, v3 -------
__global__ __launch_bounds__(256) void k_init(float* __restrict__ zp, int zn,
                                              const int* __restrict__ batch,
                                              int* __restrict__ gstart,
                                              const float* __restrict__ W2,
                                              const float* __restrict__ W7,
                                              const float* __restrict__ W3,
                                              const float* __restrict__ W4,
                                              ushort* __restrict__ wpack,
                                              float* __restrict__ v3) {
    int idx = blockIdx.x * 256 + threadIdx.x;
    if (idx < zn) zp[idx] = 0.f;
    if (idx <= NGRAPH) {
        int lo = 0, hi = N_NODES;
        while (lo < hi) {
            int mid = (lo + hi) >> 1;
            if (batch[mid] < idx) lo = mid + 1; else hi = mid;
        }
        gstart[idx] = lo;
    }
    if (idx < 4 * 16384) {
        int m = idx >> 14, f = idx & 16383;
        int j = f & 7, lane = (f >> 3) & 63, kk = (f >> 9) & 3, t = (f >> 11) & 7;
        int hp = t * 16 + (lane & 15);
        int k  = kk * 32 + ((lane >> 4) & 3) * 8 + j;
        const float* src = (m < 3) ? (W2 + m * HID * HID) : W7;
        wpack[idx] = (ushort)bf16r(src[hp * HID + k]);
    }
    if (idx < 3 * HID) {
        int l = idx / HID, hp = idx % HID;
        float acc = 0.f;
        for (int h = 0; h < HID; h++)
            acc += W3[l * HID * HID + hp * HID + h] * fmaxf(W4[l * HID + h], 0.f);
        v3[idx] = acc;
    }
}

// ---------------- P1: per-(bucket,block) histogram ----------------
__global__ __launch_bounds__(1024) void k_p1_hist(const int* __restrict__ row,
                                                  int* __restrict__ blkhist) {
    __shared__ int hist[NB];
    int tid = threadIdx.x, blk = blockIdx.x;
    for (int i = tid; i < NB; i += 1024) hist[i] = 0;
    __syncthreads();
    int s = blk * EPB, e = s + EPB; if (e > N_EDGES) e = N_EDGES;
    for (int i = s + tid; i < e; i += 1024)
        atomicAdd(&hist[row[i] >> 7], 1);
    __syncthreads();
    for (int i = tid; i < NB; i += 1024)
        blkhist[i * NBLK + blk] = hist[i];
}

// ------- P2 (fused): per-bucket scan over NBLK counts; last block scans bucket totals -------
__global__ __launch_bounds__(NBLK) void k_p2(int* __restrict__ blkhist,
                                             int* __restrict__ btot,
                                             int* __restrict__ bbase,
                                             int* __restrict__ done) {
    __shared__ int sums[NBLK];
    __shared__ int lastflag;
    int t = threadIdx.x, b = blockIdx.x;
    int v = blkhist[b * NBLK + t];
    sums[t] = v;
    __syncthreads();
    for (int d = 1; d < NBLK; d <<= 1) {
        int u = (t >= d) ? sums[t - d] : 0;
        __syncthreads();
        sums[t] += u;
        __syncthreads();
    }
    blkhist[b * NBLK + t] = sums[t] - v;     // local exclusive
    if (t == NBLK - 1) btot[b] = sums[t];    // bucket total
    if (t == 0) {
        __threadfence();
        int old = atomicAdd(done, 1);
        lastflag = (old == NB - 1);
    }
    __syncthreads();
    if (lastflag) {
        int i0 = 2 * t, i1 = 2 * t + 1;
        int v0 = (i0 < NB) ? atomicAdd(&btot[i0], 0) : 0;
        int v1 = (i1 < NB) ? atomicAdd(&btot[i1], 0) : 0;
        int sum = v0 + v1;
        sums[t] = sum;
        __syncthreads();
        for (int d = 1; d < NBLK; d <<= 1) {
            int u = (t >= d) ? sums[t - d] : 0;
            __syncthreads();
            sums[t] += u;
            __syncthreads();
        }
        int excl = sums[t] - sum;
        if (i0 < NB) bbase[i0] = excl;
        if (i1 < NB) bbase[i1] = excl + v0;
        if (t == NBLK - 1) bbase[NB] = sums[t]; // == E
    }
}

// ------- P3: scatter int2{rowlocal:8|col:16, ea} into bucket runs (LDS cursors) -------
__global__ __launch_bounds__(1024) void k_p3_part(const int* __restrict__ row,
                                                  const int* __restrict__ col,
                                                  const float* __restrict__ ea,
                                                  const int* __restrict__ blkhist,
                                                  const int* __restrict__ bbase,
                                                  int2* __restrict__ pea) {
    __shared__ int cur[NB];
    int tid = threadIdx.x, blk = blockIdx.x;
    for (int i = tid; i < NB; i += 1024)
        cur[i] = bbase[i] + blkhist[i * NBLK + blk];
    __syncthreads();
    int s = blk * EPB, e = s + EPB; if (e > N_EDGES) e = N_EDGES;
    for (int i = s + tid; i < e; i += 1024) {
        int r = row[i], c = col[i];
        float a = ea[i];
        int slot = atomicAdd(&cur[r >> 7], 1);
        pea[slot] = make_int2(((r & (RPB - 1)) << 16) | c, __float_as_int(a));
    }
}

// ------- P4a: per-bucket counts + ea_sum + local scan -> offs, pxe -------
__global__ __launch_bounds__(512) void k_p4a(const int2* __restrict__ pea,
                                             const int* __restrict__ bbase,
                                             const float* __restrict__ x,
                                             int* __restrict__ offs,
                                             float* __restrict__ ea_sum,
                                             float2* __restrict__ pxe) {
    __shared__ int   cnt[RPB];
    __shared__ float eas[RPB];
    __shared__ int   scan_s[RPB];
    int tid = threadIdx.x, b = blockIdx.x;
    if (tid < RPB) { cnt[tid] = 0; eas[tid] = 0.f; }
    __syncthreads();
    int s = bbase[b], e = bbase[b + 1];
    for (int i = s + tid; i < e; i += 512) {
        int2 p = pea[i];
        int lr = ((uint32)p.x) >> 16;
        atomicAdd(&cnt[lr], 1);
        atomicAdd(&eas[lr], __int_as_float(p.y));
    }
    __syncthreads();
    if (tid < RPB) scan_s[tid] = cnt[tid];
    __syncthreads();
    for (int d = 1; d < RPB; d <<= 1) {
        int v = 0;
        if (tid < RPB && tid >= d) v = scan_s[tid - d];
        __syncthreads();
        if (tid < RPB) scan_s[tid] += v;
        __syncthreads();
    }
    int nbase = b * RPB;
    if (tid < RPB) {
        int excl = scan_s[tid] - cnt[tid];
        int n = nbase + tid;
        if (n < N_NODES) {
            offs[n] = s + excl;
            ea_sum[n] = eas[tid];
            pxe[n] = make_float2(x[n], eas[tid]);
        }
    }
    if (b == NB - 1 && tid == 0) offs[N_NODES] = e;
}

// ------- P4b: scatter csr + CSR-ordered payload pxec[slot] = pxe[col] -------
__global__ __launch_bounds__(512) void k_p4b(const int2* __restrict__ pea,
                                             const int* __restrict__ bbase,
                                             const int* __restrict__ offs,
                                             const float2* __restrict__ pxe,
                                             int* __restrict__ csr,
                                             float2* __restrict__ pxec) {
    __shared__ int cur[RPB];
    int tid = threadIdx.x, b = blockIdx.x;
    int nbase = b * RPB;
    if (tid < RPB) cur[tid] = (nbase + tid < N_NODES) ? offs[nbase + tid] : 0;
    __syncthreads();
    int s = bbase[b], e = bbase[b + 1];
    for (int i = s + tid; i < e; i += 512) {
        int2 p = pea[i];
        int c = p.x & 0xFFFF;
        int slot = atomicAdd(&cur[((uint32)p.x) >> 16], 1);
        csr[slot] = c;
        pxec[slot] = pxe[c];   // 400 KB table, L2-resident
    }
}

// ------- hop-1 gather by recompute, streaming CSR-ordered payload (no indirection) -------
__global__ __launch_bounds__(256) void k_gather1(const float2* __restrict__ pxec,
                                                 const int* __restrict__ offs,
                                                 const float* __restrict__ w1,
                                                 const float* __restrict__ v3,
                                                 uint32* __restrict__ agg) {
    int node = (blockIdx.x * 256 + threadIdx.x) >> 6;
    int lane = threadIdx.x & 63;
    if (node >= N_NODES) return;
    f32x2 w1v = {w1[2 * lane], w1[2 * lane + 1]};
    f32x2 v3v = {v3[2 * lane], v3[2 * lane + 1]};
    const f32x2 zero = {0.f, 0.f};
    int s = offs[node], e = offs[node + 1];
    f32x2 acc[4] = {zero, zero, zero, zero};
    int j = s;
    for (; j + 8 <= e; j += 8) {
        float2 p[8];
#pragma unroll
        for (int u = 0; u < 8; u++) p[u] = pxec[j + u];   // broadcast, contiguous
#pragma unroll
        for (int u = 0; u < 8; u++) {
            f32x2 px = {p[u].x, p[u].x};
            f32x2 pe = {p[u].y, p[u].y};
            f32x2 r = __builtin_elementwise_fma(px, w1v, pe * v3v);
            acc[u & 3] += __builtin_elementwise_max(r, zero);
        }
    }
    for (; j < e; j++) {
        float2 p = pxec[j];
        f32x2 px = {p.x, p.x};
        f32x2 pe = {p.y, p.y};
        f32x2 r = __builtin_elementwise_fma(px, w1v, pe * v3v);
        acc[0] += __builtin_elementwise_max(r, zero);
    }
    f32x2 rs = (acc[0] + acc[1]) + (acc[2] + acc[3]);
    agg[(size_t)node * 64 + lane] = pack_bf16(rs.x, rs.y);
}

// ------- hop-2 gather, split-wave: 2 edges/iter, dword fp8 loads (4 vals/lane) -------
// half = lane>>5 picks edge j+half; lane covers h = 4*(lane&31)..+3; merge via shfl_xor(32)
__global__ __launch_bounds__(256) void k_gather(const uchar* __restrict__ emb8,
                                                const int* __restrict__ offs,
                                                const int* __restrict__ csr,
                                                uint32* __restrict__ agg) {
    int node = (blockIdx.x * 256 + threadIdx.x) >> 6;
    int lane = threadIdx.x & 63;
    if (node >= N_NODES) return;
    int half = lane >> 5, hl = lane & 31;
    int s = offs[node], e = offs[node + 1];
    float a0[4] = {0.f, 0.f, 0.f, 0.f}, a1[4] = {0.f, 0.f, 0.f, 0.f};
    for (int base = s; base < e; base += 64) {
        int idx = base + lane;
        int cv = (idx < e) ? csr[idx] : 0;     // one coalesced load per 64 edges
        int cnt = e - base; if (cnt > 64) cnt = 64;
        int j = 0;
        for (; j + 16 <= cnt; j += 16) {       // 8 pair-iterations = 16 edges, 8 loads in flight
            uint32 u[8];
#pragma unroll
            for (int t = 0; t < 8; t++) {
                int c = __shfl(cv, j + 2 * t + half);
                u[t] = *(const uint32*)(emb8 + (size_t)c * 128 + hl * 4);
            }
#pragma unroll
            for (int t = 0; t < 8; t++) {
                f32x2 dlo = __builtin_amdgcn_cvt_pk_f32_fp8((int)u[t], false);
                f32x2 dhi = __builtin_amdgcn_cvt_pk_f32_fp8((int)u[t], true);
                if (t & 1) { a1[0] += dlo.x; a1[1] += dlo.y; a1[2] += dhi.x; a1[3] += dhi.y; }
                else       { a0[0] += dlo.x; a0[1] += dlo.y; a0[2] += dhi.x; a0[3] += dhi.y; }
            }
        }
        for (; j < cnt; j += 2) {              // remainder pairs (tail may be odd)
            int jj = j + half;
            bool valid = jj < cnt;
            int c = __shfl(cv, valid ? jj : 0);
            uint32 u = *(const uint32*)(emb8 + (size_t)c * 128 + hl * 4);
            if (!valid) u = 0u;
            f32x2 dlo = __builtin_amdgcn_cvt_pk_f32_fp8((int)u, false);
            f32x2 dhi = __builtin_amdgcn_cvt_pk_f32_fp8((int)u, true);
            a0[0] += dlo.x; a0[1] += dlo.y; a0[2] += dhi.x; a0[3] += dhi.y;
        }
    }
    float v0 = a0[0] + a1[0], v1 = a0[1] + a1[1], v2 = a0[2] + a1[2], v3 = a0[3] + a1[3];
    v0 += __shfl_xor(v0, 32);   // merge the two halves
    v1 += __shfl_xor(v1, 32);
    v2 += __shfl_xor(v2, 32);
    v3 += __shfl_xor(v3, 32);
    if (half == 0) {
        uint2 r;
        r.x = pack_bf16(v0 * 64.f, v1 * 64.f);
        r.y = pack_bf16(v2 * 64.f, v3 * 64.f);
        ((uint2*)agg)[(size_t)node * 32 + hl] = r;
    }
}

#define LROW 136  // padded LDS row, bf16 elems

// ------- MFMA GEMM hop: emb = relu(agg @ W2T + x*w1 + ea*v3) -------
// !LAST: emit fp8 emb (scale 2^-6, row 128 B). LAST: emit bf16 emb + fused W7-head.
template <bool LAST>
__global__ __launch_bounds__(256) void k_gemm(const uint32* __restrict__ agg,   // bf16 [N][64u32]
                                              const ushort* __restrict__ w2p,   // B-frag packed
                                              const float* __restrict__ w1l,
                                              const float* __restrict__ v3l,
                                              const float* __restrict__ x,
                                              const float* __restrict__ ea_sum,
                                              uint32* __restrict__ embOut,      // bf16 (LAST)
                                              uchar* __restrict__ emb8Out,      // fp8 (!LAST)
                                              const ushort* __restrict__ w7p,
                                              const float* __restrict__ W5,
                                              float* __restrict__ outp) {
    __shared__ ushort tile[64 * LROW]; // 17408 B
    int tid = threadIdx.x;
    int tbase = blockIdx.x * 64;
    {
        const uint2* src = (const uint2*)(agg + (size_t)tbase * 64);
        int vn = N_NODES - tbase; if (vn > 64) vn = 64;
        int lim = vn * 32;
        for (int i = tid; i < 64 * 32; i += 256) {
            uint2 u = (i < lim) ? src[i] : make_uint2(0u, 0u);
            int r = i >> 5, c4 = (i & 31) * 4;
            *(uint2*)&tile[r * LROW + c4] = u;
        }
    }
    __syncthreads();
    int wv = tid >> 6, lane = tid & 63;
    int n0 = lane & 15, quad = lane >> 4;
    int arow = wv * 16 + n0;
    bf16x8 a0 = *(const bf16x8*)&tile[arow * LROW + 0 * 32 + quad * 8];
    bf16x8 a1 = *(const bf16x8*)&tile[arow * LROW + 1 * 32 + quad * 8];
    bf16x8 a2 = *(const bf16x8*)&tile[arow * LROW + 2 * 32 + quad * 8];
    bf16x8 a3 = *(const bf16x8*)&tile[arow * LROW + 3 * 32 + quad * 8];
    const bf16x8* wb = (const bf16x8*)w2p;
    f32x4 acc[8];
#pragma unroll
    for (int t = 0; t < 8; t++) {
        f32x4 c = {0.f, 0.f, 0.f, 0.f};
        c = __builtin_amdgcn_mfma_f32_16x16x32_bf16(a0, wb[(t * 4 + 0) * 64 + lane], c, 0, 0, 0);
        c = __builtin_amdgcn_mfma_f32_16x16x32_bf16(a1, wb[(t * 4 + 1) * 64 + lane], c, 0, 0, 0);
        c = __builtin_amdgcn_mfma_f32_16x16x32_bf16(a2, wb[(t * 4 + 2) * 64 + lane], c, 0, 0, 0);
        c = __builtin_amdgcn_mfma_f32_16x16x32_bf16(a3, wb[(t * 4 + 3) * 64 + lane], c, 0, 0, 0);
        acc[t] = c;
    }
    float xs[4], es[4];
#pragma unroll
    for (int r = 0; r < 4; r++) {
        int n = tbase + wv * 16 + quad * 4 + r;
        xs[r] = (n < N_NODES) ? x[n] : 0.f;
        es[r] = (n < N_NODES) ? ea_sum[n] : 0.f;
    }
    if (!LAST) {
        // epilogue: fp8 output, scale 2^-6 (exact pow2; rescaled x64 in k_gather)
        uchar* stile = (uchar*)tile;   // rows stride 136 B; wave-private rows
#pragma unroll
        for (int t = 0; t < 8; t++) {
            int hp = t * 16 + n0;
            float w1v = w1l[hp], v3v = v3l[hp];
#pragma unroll
            for (int r = 0; r < 4; r++) {
                float v = fmaxf(acc[t][r] + xs[r] * w1v + es[r] * v3v, 0.f) * 0.015625f;
                int enc = __builtin_amdgcn_cvt_pk_fp8_f32(v, v, 0, false);
                stile[(wv * 16 + quad * 4 + r) * 136 + hp] = (uchar)(enc & 0xff);
            }
        }
        __syncthreads();
        int vn = N_NODES - tbase; if (vn > 64) vn = 64;
        for (int i = tid; i < 64 * 32; i += 256) {
            int r = i >> 5, c4 = (i & 31) * 4;
            if (r < vn) {
                uint32 u = *(const uint32*)&stile[r * 136 + c4];
                *(uint32*)(emb8Out + (size_t)(tbase + r) * 128 + c4) = u;
            }
        }
    } else {
        // epilogue: bf16 output back through LDS + fused W7 head
#pragma unroll
        for (int t = 0; t < 8; t++) {
            int hp = t * 16 + n0;
            float w1v = w1l[hp], v3v = v3l[hp];
#pragma unroll
            for (int r = 0; r < 4; r++) {
                float v = fmaxf(acc[t][r] + xs[r] * w1v + es[r] * v3v, 0.f);
                tile[(wv * 16 + quad * 4 + r) * LROW + hp] = (ushort)bf16r(v);
            }
        }
        __syncthreads();
        {
            int vn = N_NODES - tbase; if (vn > 64) vn = 64;
            for (int i = tid; i < 64 * 32; i += 256) {
                int r = i >> 5, c4 = (i & 31) * 4;
                if (r < vn) {
                    uint2 u = *(const uint2*)&tile[r * LROW + c4];
                    *(uint2*)(embOut + (size_t)(tbase + r) * 64 + (size_t)(i & 31) * 2) = u;
                }
            }
        }
        bf16x8 b0 = *(const bf16x8*)&tile[arow * LROW + 0 * 32 + quad * 8];
        bf16x8 b1 = *(const bf16x8*)&tile[arow * LROW + 1 * 32 + quad * 8];
        bf16x8 b2 = *(const bf16x8*)&tile[arow * LROW + 2 * 32 + quad * 8];
        bf16x8 b3 = *(const bf16x8*)&tile[arow * LROW + 3 * 32 + quad * 8];
        const bf16x8* w7 = (const bf16x8*)w7p;
        float p[4] = {0.f, 0.f, 0.f, 0.f};
#pragma unroll
        for (int t = 0; t < 8; t++) {
            f32x4 c = {0.f, 0.f, 0.f, 0.f};
            c = __builtin_amdgcn_mfma_f32_16x16x32_bf16(b0, w7[(t * 4 + 0) * 64 + lane], c, 0, 0, 0);
            c = __builtin_amdgcn_mfma_f32_16x16x32_bf16(b1, w7[(t * 4 + 1) * 64 + lane], c, 0, 0, 0);
            c = __builtin_amdgcn_mfma_f32_16x16x32_bf16(b2, w7[(t * 4 + 2) * 64 + lane], c, 0, 0, 0);
            c = __builtin_amdgcn_mfma_f32_16x16x32_bf16(b3, w7[(t * 4 + 3) * 64 + lane], c, 0, 0, 0);
            float w5v = W5[128 + t * 16 + n0];
#pragma unroll
            for (int r = 0; r < 4; r++) p[r] += fmaxf(c[r], 0.f) * w5v;
        }
#pragma unroll
        for (int r = 0; r < 4; r++) {
            float v = p[r];
            v += __shfl_xor(v, 1);
            v += __shfl_xor(v, 2);
            v += __shfl_xor(v, 4);
            v += __shfl_xor(v, 8);
            int n = tbase + wv * 16 + quad * 4 + r;
            if (n0 == 0 && n < N_NODES) outp[n] = v;
        }
    }
}

// ------- pooling (fused s_g): 256 blocks; last block computes s_g = relu(pooled@W6T).W5[:128] -------
__global__ __launch_bounds__(256) void k_pool2(const uint32* __restrict__ emb,
                                               const int* __restrict__ gstart,
                                               float* __restrict__ pooled,
                                               int* __restrict__ done,
                                               const float* __restrict__ W6,
                                               const float* __restrict__ W5,
                                               float* __restrict__ s_g) {
    __shared__ float2 red[4][64];
    __shared__ int lastflag;
    int bid = blockIdx.x;
    int g = bid >> 4, chunk = bid & 15;
    int gs = gstart[g], ge = gstart[g + 1];
    int len = ge - gs;
    int cs = gs + (int)(((long long)len * chunk) >> 4);
    int ce = gs + (int)(((long long)len * (chunk + 1)) >> 4);
    int sub = threadIdx.x >> 6, lane = threadIdx.x & 63;
    float ax = 0.f, ay = 0.f;
    for (int n = cs + sub; n < ce; n += 4) {
        uint32 u = emb[(size_t)n * 64 + lane];
        ax += bf_lo(u); ay += bf_hi(u);
    }
    red[sub][lane] = make_float2(ax, ay);
    __syncthreads();
    if (sub == 0) {
        float2 r0 = red[0][lane], r1 = red[1][lane], r2 = red[2][lane], r3 = red[3][lane];
        atomicAdd(&pooled[g * HID + 2 * lane],     (r0.x + r1.x) + (r2.x + r3.x));
        atomicAdd(&pooled[g * HID + 2 * lane + 1], (r0.y + r1.y) + (r2.y + r3.y));
    }
    if (threadIdx.x == 0) {
        __threadfence();
        int old = atomicAdd(done, 1);
        lastflag = (old == (int)gridDim.x - 1);
    }
    __syncthreads();
    if (lastflag) {
        __shared__ float pool_s[NGRAPH * HID]; // 8 KB
        __shared__ float red2[NGRAPH * HID];   // 8 KB
        int tid = threadIdx.x;
        for (int i = tid; i < NGRAPH * HID; i += 256)
            pool_s[i] = atomicAdd(&pooled[i], 0.f);   // coherent read
        __syncthreads();
        if (tid < HID) {
            int hp = tid;
            float acc[NGRAPH];
#pragma unroll
            for (int gg = 0; gg < NGRAPH; gg++) acc[gg] = 0.f;
            for (int h = 0; h < HID; h++) {
                float wv = W6[hp * HID + h];
#pragma unroll
                for (int gg = 0; gg < NGRAPH; gg++)
                    acc[gg] += pool_s[gg * HID + h] * wv;
            }
            float w5v = W5[hp];
#pragma unroll
            for (int gg = 0; gg < NGRAPH; gg++)
                red2[gg * HID + hp] = fmaxf(acc[gg], 0.f) * w5v;
        }
        __syncthreads();
        if (tid < NGRAPH) {
            float s = 0.f;
            for (int h = 0; h < HID; h++) s += red2[tid * HID + h];
            s_g[tid] = s;
        }
    }
}

// ---------------- final add: out[n] += s_g[batch[n]] + b5 ----------------
__global__ __launch_bounds__(256) void k_addsg(float* __restrict__ out,
                                               const int* __restrict__ batch,
                                               const float* __restrict__ s_g,
                                               const float* __restrict__ b5) {
    int n = blockIdx.x * 256 + threadIdx.x;
    if (n < N_NODES) out[n] += s_g[batch[n]] + b5[0];
}

extern "C" void kernel_launch(void* const* d_in, const int* in_sizes, int n_in,
                              void* d_out, int out_size, void* d_ws, size_t ws_size,
                              hipStream_t stream) {
    (void)in_sizes; (void)n_in; (void)out_size; (void)ws_size;
    const float* x    = (const float*)d_in[0];
    const int*   ei   = (const int*)d_in[1];   // [2,E] flat: row then col
    const float* ea   = (const float*)d_in[2];
    const int*   bat  = (const int*)d_in[3];
    const float* W1   = (const float*)d_in[4]; // [3,128,1]
    const float* W2   = (const float*)d_in[5]; // [3,128,128]
    const float* W3   = (const float*)d_in[6];
    const float* W4   = (const float*)d_in[7]; // [3,128,1]
    const float* W5   = (const float*)d_in[8]; // [1,256]
    const float* b5   = (const float*)d_in[9];
    const float* W6   = (const float*)d_in[10];
    const float* W7   = (const float*)d_in[11];
    float* out = (float*)d_out;

    const int* row = ei;
    const int* col = ei + N_EDGES;

    // workspace layout (4B elems)
    float* wsf = (float*)d_ws;
    int*   wsi = (int*)d_ws;
    size_t o = 0;
    float* pooled = wsf + o; o += NGRAPH * HID;     // zeroed (atomic targets)
    float* s_g    = wsf + o; o += NGRAPH;           // zeroed
    int*   done_p2   = wsi + o; o += 1;             // zeroed arrival counters
    int*   done_pool = wsi + o; o += 1;
    size_t ztot = o;
    int*   offs   = wsi + o; o += N_NODES + 1;
    float* ea_sum = wsf + o; o += N_NODES;
    int*   gstart = wsi + o; o += NGRAPH + 1;
    int*   btot   = wsi + o; o += NB;
    int*   bbase  = wsi + o; o += NB + 1;
    float* v3     = wsf + o; o += 3 * HID;
    int*   blkh   = wsi + o; o += NB * NBLK;
    o = (o + 1) & ~(size_t)1;
    float2* pxe   = (float2*)(wsi + o); o += 2 * (size_t)N_NODES;
    o = (o + 3) & ~(size_t)3;
    ushort* wpack = (ushort*)(wsi + o); o += 4 * 16384 / 2;
    int*    csr   = wsi + o; o += N_EDGES;
    o = (o + 1) & ~(size_t)1;
    int2*   pea   = (int2*)(wsi + o); o += 2 * (size_t)N_EDGES;
    float2* pxec  = (float2*)(wsi + o); o += 2 * (size_t)N_EDGES;
    o = (o + 1) & ~(size_t)1;
    uint32* embA  = (uint32*)(wsi + o); o += (size_t)N_NODES * 64;  // bf16 [N][128]
    uchar*  emb8  = (uchar*)(wsi + o);  o += (size_t)N_NODES * 32;  // fp8 [N][128]
    uint32* aggB  = (uint32*)(wsi + o); o += (size_t)N_NODES * 64;  // bf16 [N][128]

    const ushort* w2p1 = wpack + 1 * 16384;
    const ushort* w2p2 = wpack + 2 * 16384;
    const ushort* w7p  = wpack + 3 * 16384;

    // 0) init: zero accumulators/counters + graph bounds + weight pack + v3 (fused)
    k_init<<<256, 256, 0, stream>>>((float*)d_ws, (int)ztot, bat, gstart,
                                    W2, W7, W3, W4, (ushort*)wpack, v3);
    // 1) atomic-free CSR build + CSR-ordered hop-1 payload
    k_p1_hist<<<NBLK, 1024, 0, stream>>>(row, blkh);
    k_p2<<<NB, NBLK, 0, stream>>>(blkh, btot, bbase, done_p2);
    k_p3_part<<<NBLK, 1024, 0, stream>>>(row, col, ea, blkh, bbase, pea);
    k_p4a<<<NB, 512, 0, stream>>>(pea, bbase, x, offs, ea_sum, pxe);
    k_p4b<<<NB, 512, 0, stream>>>(pea, bbase, offs, pxe, csr, pxec);
    // 2) hop 1: streaming recompute-gather -> aggB ; MFMA gemm -> fp8 emb
    k_gather1<<<(N_NODES * 64 + 255) / 256, 256, 0, stream>>>(pxec, offs, W1, v3, aggB);
    k_gemm<false><<<(N_NODES + 63) / 64, 256, 0, stream>>>(
        aggB, w2p1, W1 + 1 * HID, v3 + 1 * HID, x, ea_sum, nullptr, emb8, nullptr, nullptr, nullptr);
    // 3) hop 2: split-wave fp8 gather -> aggB ; MFMA gemm + W7 head -> embA, out partial
    k_gather<<<(N_NODES * 64 + 255) / 256, 256, 0, stream>>>(emb8, offs, csr, aggB);
    k_gemm<true><<<(N_NODES + 63) / 64, 256, 0, stream>>>(
        aggB, w2p2, W1 + 2 * HID, v3 + 2 * HID, x, ea_sum, embA, nullptr, w7p, W5, out);
    // 4) graph pooling + fused s_g (last-block)
    k_pool2<<<NGRAPH * 16, 256, 0, stream>>>(embA, gstart, pooled, done_pool, W6, W5, s_g);
    // 5) add graph term + bias
    k_addsg<<<(N_NODES + 255) / 256, 256, 0, stream>>>(out, bat, s_g, b5);
}